// Round 1
// baseline (367.088 us; speedup 1.0000x reference)
//
#include <hip/hip_runtime.h>

// Problem constants
#define M_DIM 8192   // 4*2048
#define N_DIM 4096   // OUT
#define K_DIM 4096   // IN
#define L_BLK 2097152  // OUT*IN/8

typedef __attribute__((ext_vector_type(8))) short short8;
typedef __attribute__((ext_vector_type(8))) unsigned short ushort8;
typedef __attribute__((ext_vector_type(4))) float f32x4;

__device__ __forceinline__ unsigned short f2bf(float f) {
  unsigned int u = __float_as_uint(f);
  unsigned int r = (u + 0x7fffu + ((u >> 16) & 1u)) >> 16;
  return (unsigned short)r;
}

__device__ __forceinline__ void gld16(const void* g, void* l) {
  __builtin_amdgcn_global_load_lds(
      (const __attribute__((address_space(1))) void*)g,
      (__attribute__((address_space(3))) void*)l, 16, 0, 0);
}

// ---------------- Dequant: Wq[o,i] = scale[o] * (clip(base + r + zero, 0, 15) - zero[o])
__global__ void dequant_kernel(const float* __restrict__ cb,
                               const int* __restrict__ idx,
                               const int* __restrict__ base,
                               const float* __restrict__ scale,
                               const float* __restrict__ zero,
                               unsigned short* __restrict__ W) {
  const int b = blockIdx.x * 256 + threadIdx.x;   // one per 8-elem block
  const int o = b >> 9;                            // (b*8)/4096
  const float s = scale[o];
  const float z = zero[o];
  const int ci = idx[b];
  const float4* crow = (const float4*)(cb + (size_t)ci * 8);
  float4 c0 = crow[0], c1 = crow[1];
  const int4* brow = (const int4*)(base + (size_t)b * 8);
  int4 b0 = brow[0], b1 = brow[1];
  float a[8]  = {c0.x, c0.y, c0.z, c0.w, c1.x, c1.y, c1.z, c1.w};
  int   bi[8] = {b0.x, b0.y, b0.z, b0.w, b1.x, b1.y, b1.z, b1.w};
  union { unsigned short h[8]; ushort8 v; } u;
#pragma unroll
  for (int d = 0; d < 8; ++d) {
    float sg = 1.0f / (1.0f + __expf(-a[d]));
    float r = fminf(fmaxf(sg * 1.2f - 0.1f, 0.0f), 1.0f);
    float q = fminf(fmaxf((float)bi[d] + r + z, 0.0f), 15.0f);
    u.h[d] = f2bf(s * (q - z));
  }
  *(ushort8*)(W + (size_t)b * 8) = u.v;
}

// ---------------- x f32 -> bf16
__global__ void xconv_kernel(const float* __restrict__ x,
                             unsigned short* __restrict__ xb) {
  const size_t i = (size_t)blockIdx.x * 256 + threadIdx.x;  // 8 floats each
  const float4* X = (const float4*)x;
  float4 a0 = X[i * 2], a1 = X[i * 2 + 1];
  float f[8] = {a0.x, a0.y, a0.z, a0.w, a1.x, a1.y, a1.z, a1.w};
  union { unsigned short h[8]; ushort8 v; } u;
#pragma unroll
  for (int d = 0; d < 8; ++d) u.h[d] = f2bf(f[d]);
  *(ushort8*)(xb + i * 8) = u.v;
}

// ---------------- GEMM: C[m,n] = sum_k A[m,k]*B[n,k] + bias[n]
// A: [M,K] bf16 row-major, B: [N,K] bf16 row-major (B^T GEMM), C: [M,N] f32.
// m97 structure: 128x128 tile, BK=64, 4 waves (2x2), 16x16x32 MFMA,
// global_load_lds width=16 into linear LDS, 2 barriers per K-step.
__global__ void gemm_bt(const unsigned short* __restrict__ A,
                        const unsigned short* __restrict__ B,
                        const float* __restrict__ bias,
                        float* __restrict__ C) {
  __shared__ char lds[2 * 128 * 64 * 2];  // sA | sB, 16 KB each
  char* sA = lds;
  char* sB = lds + 128 * 64 * 2;

  const int tid = threadIdx.x;
  const int lane = tid & 63;
  const int w = tid >> 6;
  const int bid = blockIdx.x;
  const int bn = bid & 31;   // N/128 = 32
  const int bm = bid >> 5;   // M/128 = 64

  const char* Abase = (const char*)A + (size_t)(bm * 128) * (K_DIM * 2);
  const char* Bbase = (const char*)B + (size_t)(bn * 128) * (K_DIM * 2);

  const int wm = (w >> 1) * 64;   // wave row offset in tile
  const int wn = (w & 1) * 64;    // wave col offset in tile
  const int r16 = lane & 15;
  const int g = lane >> 4;

  f32x4 acc[4][4] = {};

  // staging: per round r (0..3), wave w writes LDS bytes [(r*4+w)*1024, +1024)
  const int soff = w * 1024 + lane * 16;

  for (int k0 = 0; k0 < K_DIM; k0 += 64) {
    const char* Ak = Abase + k0 * 2;
    const char* Bk = Bbase + k0 * 2;
#pragma unroll
    for (int r = 0; r < 4; ++r) {
      int t = r * 4096 + soff;      // linear byte offset in 16KB tile
      int row = t >> 7;             // 128 B per row (64 bf16)
      int colb = t & 127;
      gld16(Ak + (size_t)row * (K_DIM * 2) + colb, sA + r * 4096 + w * 1024);
      gld16(Bk + (size_t)row * (K_DIM * 2) + colb, sB + r * 4096 + w * 1024);
    }
    __syncthreads();
#pragma unroll
    for (int kk = 0; kk < 2; ++kk) {
      short8 a[4], b[4];
#pragma unroll
      for (int m = 0; m < 4; ++m)
        a[m] = *(const short8*)(sA + (wm + m * 16 + r16) * 128 + kk * 64 + g * 16);
#pragma unroll
      for (int n = 0; n < 4; ++n)
        b[n] = *(const short8*)(sB + (wn + n * 16 + r16) * 128 + kk * 64 + g * 16);
#pragma unroll
      for (int m = 0; m < 4; ++m)
#pragma unroll
        for (int n = 0; n < 4; ++n)
          acc[m][n] = __builtin_amdgcn_mfma_f32_16x16x32_bf16(a[m], b[n], acc[m][n], 0, 0, 0);
    }
    __syncthreads();
  }

  // epilogue: C/D layout col = lane&15, row = (lane>>4)*4 + j  [m89-verified]
  float bv[4];
#pragma unroll
  for (int n = 0; n < 4; ++n) bv[n] = bias[bn * 128 + wn + n * 16 + r16];
#pragma unroll
  for (int m = 0; m < 4; ++m) {
#pragma unroll
    for (int j = 0; j < 4; ++j) {
      int row = bm * 128 + wm + m * 16 + g * 4 + j;
      float* Crow = C + (size_t)row * N_DIM + bn * 128 + wn + r16;
#pragma unroll
      for (int n = 0; n < 4; ++n) Crow[n * 16] = acc[m][n][j] + bv[n];
    }
  }
}

extern "C" void kernel_launch(void* const* d_in, const int* in_sizes, int n_in,
                              void* d_out, int out_size, void* d_ws, size_t ws_size,
                              hipStream_t stream) {
  const float* x     = (const float*)d_in[0];
  const float* cb    = (const float*)d_in[1];
  const int*   idx   = (const int*)d_in[2];
  const int*   base  = (const int*)d_in[3];
  const float* scale = (const float*)d_in[4];
  const float* zero  = (const float*)d_in[5];
  const float* bias  = (const float*)d_in[6];
  float* out = (float*)d_out;

  // workspace: Wq bf16 [N,K] (32 MiB) | x bf16 [M,K] (64 MiB)
  unsigned short* Wq = (unsigned short*)d_ws;
  unsigned short* Xb = (unsigned short*)((char*)d_ws + (size_t)N_DIM * K_DIM * 2);

  dequant_kernel<<<L_BLK / 256, 256, 0, stream>>>(cb, idx, base, scale, zero, Wq);
  xconv_kernel<<<(M_DIM * K_DIM / 8) / 256, 256, 0, stream>>>(x, Xb);
  gemm_bt<<<(M_DIM / 128) * (N_DIM / 128), 256, 0, stream>>>(Xb, Wq, bias, out);
}

// Round 2
// 322.346 us; speedup vs baseline: 1.1388x; 1.1388x over previous
//
#include <hip/hip_runtime.h>

// Problem constants
#define M_DIM 8192   // 4*2048
#define N_DIM 4096   // OUT
#define K_DIM 4096   // IN
#define L_BLK 2097152  // OUT*IN/8
#define K2 8192      // bytes per bf16 row of K_DIM

typedef __attribute__((ext_vector_type(8))) short short8;
typedef __attribute__((ext_vector_type(8))) unsigned short ushort8;
typedef __attribute__((ext_vector_type(4))) float f32x4;

__device__ __forceinline__ unsigned short f2bf(float f) {
  unsigned int u = __float_as_uint(f);
  unsigned int r = (u + 0x7fffu + ((u >> 16) & 1u)) >> 16;
  return (unsigned short)r;
}

__device__ __forceinline__ void gld16(const void* g, void* l) {
  __builtin_amdgcn_global_load_lds(
      (const __attribute__((address_space(1))) void*)g,
      (__attribute__((address_space(3))) void*)l, 16, 0, 0);
}

// ---------------- Dequant: Wq[o,i] = scale[o] * (clip(base + r + zero, 0, 15) - zero[o])
__global__ void dequant_kernel(const float* __restrict__ cb,
                               const int* __restrict__ idx,
                               const int* __restrict__ base,
                               const float* __restrict__ scale,
                               const float* __restrict__ zero,
                               unsigned short* __restrict__ W) {
  const int b = blockIdx.x * 256 + threadIdx.x;   // one per 8-elem block
  const int o = b >> 9;                            // (b*8)/4096
  const float s = scale[o];
  const float z = zero[o];
  const int ci = idx[b];
  const float4* crow = (const float4*)(cb + (size_t)ci * 8);
  float4 c0 = crow[0], c1 = crow[1];
  const int4* brow = (const int4*)(base + (size_t)b * 8);
  int4 b0 = brow[0], b1 = brow[1];
  float a[8]  = {c0.x, c0.y, c0.z, c0.w, c1.x, c1.y, c1.z, c1.w};
  int   bi[8] = {b0.x, b0.y, b0.z, b0.w, b1.x, b1.y, b1.z, b1.w};
  union { unsigned short h[8]; ushort8 v; } u;
#pragma unroll
  for (int d = 0; d < 8; ++d) {
    float sg = 1.0f / (1.0f + __expf(-a[d]));
    float r = fminf(fmaxf(sg * 1.2f - 0.1f, 0.0f), 1.0f);
    float q = fminf(fmaxf((float)bi[d] + r + z, 0.0f), 15.0f);
    u.h[d] = f2bf(s * (q - z));
  }
  *(ushort8*)(W + (size_t)b * 8) = u.v;
}

// ---------------- x f32 -> bf16
__global__ void xconv_kernel(const float* __restrict__ x,
                             unsigned short* __restrict__ xb) {
  const size_t i = (size_t)blockIdx.x * 256 + threadIdx.x;  // 8 floats each
  const float4* X = (const float4*)x;
  float4 a0 = X[i * 2], a1 = X[i * 2 + 1];
  float f[8] = {a0.x, a0.y, a0.z, a0.w, a1.x, a1.y, a1.z, a1.w};
  union { unsigned short h[8]; ushort8 v; } u;
#pragma unroll
  for (int d = 0; d < 8; ++d) u.h[d] = f2bf(f[d]);
  *(ushort8*)(xb + i * 8) = u.v;
}

// ---------------- GEMM: C[m,n] = sum_k A[m,k]*B[n,k] + bias[n]
// 256x256 tile, BK=64, 8 waves (2Mx4N), 8-phase-style schedule (4 phases/K-tile,
// counted vmcnt, raw barriers, setprio around MFMA), XOR-swizzled LDS
// (off ^= (row&7)<<4, applied on global source + read address, linear gld dest).

#define BAR __builtin_amdgcn_s_barrier()
#define LGKM0 do { asm volatile("s_waitcnt lgkmcnt(0)" ::: "memory"); \
                   __builtin_amdgcn_sched_barrier(0); } while (0)
#define VMW(N) asm volatile("s_waitcnt vmcnt(" #N ")" ::: "memory")

#define RD_B_ALL(BUFO) \
  _Pragma("unroll") for (int n = 0; n < 4; ++n) \
  _Pragma("unroll") for (int kk = 0; kk < 2; ++kk) \
    bf[n][kk] = *(const short8*)(lds + (BUFO) + 32768 + \
        (wn * 64 + n * 16 + r16) * 128 + (acol0 ^ (kk << 6)));

#define RD_A_PAIR(BUFO, P) \
  _Pragma("unroll") for (int mi = 0; mi < 2; ++mi) \
  _Pragma("unroll") for (int kk = 0; kk < 2; ++kk) \
    af[mi][kk] = *(const short8*)(lds + (BUFO) + \
        (wm * 128 + (2 * (P) + mi) * 16 + r16) * 128 + (acol0 ^ (kk << 6)));

#define MFMA_PAIR(P) do { \
  __builtin_amdgcn_s_setprio(1); \
  _Pragma("unroll") for (int kk = 0; kk < 2; ++kk) \
  _Pragma("unroll") for (int mi = 0; mi < 2; ++mi) \
  _Pragma("unroll") for (int n = 0; n < 4; ++n) \
    acc[2 * (P) + mi][n] = __builtin_amdgcn_mfma_f32_16x16x32_bf16( \
        af[mi][kk], bf[n][kk], acc[2 * (P) + mi][n], 0, 0, 0); \
  __builtin_amdgcn_s_setprio(0); \
} while (0)

__global__ __launch_bounds__(512, 2)
void gemm_bt(const unsigned short* __restrict__ A,
             const unsigned short* __restrict__ B,
             const float* __restrict__ bias,
             float* __restrict__ C) {
  __shared__ char lds[131072];  // 2 bufs x (A 32K | B 32K)
  const int tid = threadIdx.x;
  const int lane = tid & 63;
  const int w = tid >> 6;       // 0..7
  const int wm = w >> 2;        // 0..1  (wave row: 128 rows each)
  const int wn = w & 3;         // 0..3  (wave col: 64 cols each)
  const int r16 = lane & 15;
  const int g = lane >> 4;
  const int swr = (r16 & 7) << 4;
  const int acol0 = (g << 4) ^ swr;   // + (kk<<6) via XOR

  // XCD-bijective block swizzle (512 % 8 == 0): consecutive wg within an XCD,
  // bn-major chunks so each XCD reuses 2 B-panels (4 MB) from its L2.
  const int s = (int)blockIdx.x;
  const int wg = (s & 7) * 64 + (s >> 3);
  const int bm = wg & 31;
  const int bn = wg >> 5;

  const char* Abase = (const char*)A + (size_t)bm * 256 * K2;
  const char* Bbase = (const char*)B + (size_t)bn * 256 * K2;

  // staging constants: chunk = 8 KiB = 64 rows x 128 B; thread covers 16 B
  const int strow = tid >> 3;                          // row within chunk
  const int scol = ((tid & 7) * 16) ^ ((strow & 7) << 4);  // inverse-swizzled src col
  const int sdst = w * 1024;                           // wave-uniform dest offset

  auto stA = [&](int bo, int c, int kt) {
    gld16(Abase + (size_t)(c * 64 + strow) * K2 + kt * 128 + scol,
          lds + bo + c * 8192 + sdst);
  };
  auto stB = [&](int bo, int c, int kt) {
    gld16(Bbase + (size_t)(c * 64 + strow) * K2 + kt * 128 + scol,
          lds + bo + 32768 + c * 8192 + sdst);
  };

  f32x4 acc[8][4] = {};
  short8 bf[4][2];
  short8 af[2][2];

  // prologue: stage tile 0 into buf 0, drain once
  stB(0, 0, 0); stB(0, 1, 0); stB(0, 2, 0); stB(0, 3, 0);
  stA(0, 0, 0); stA(0, 1, 0); stA(0, 2, 0); stA(0, 3, 0);
  VMW(0);
  BAR;

  int bufo = 0;
  for (int t = 0; t < 63; ++t) {
    const int nxt = bufo ^ 65536;
    const int kt = t + 1;
    // phase 0: B frags + A m{0,1}; stage B chunks 0,1 of next tile
    RD_B_ALL(bufo); RD_A_PAIR(bufo, 0);
    stB(nxt, 0, kt); stB(nxt, 1, kt);
    BAR; LGKM0; MFMA_PAIR(0); BAR;
    // phase 1: A m{2,3}; stage B chunks 2,3; wait late-A of current tile
    RD_A_PAIR(bufo, 1);
    stB(nxt, 2, kt); stB(nxt, 3, kt);
    VMW(4);
    BAR; LGKM0; MFMA_PAIR(1); BAR;
    // phase 2: A m{4,5}; stage A chunks 0,2
    RD_A_PAIR(bufo, 2);
    stA(nxt, 0, kt); stA(nxt, 2, kt);
    BAR; LGKM0; MFMA_PAIR(2); BAR;
    // phase 3: A m{6,7}; stage A chunks 1,3; wait 6 oldest (next tile ph0/1 needs)
    RD_A_PAIR(bufo, 3);
    stA(nxt, 1, kt); stA(nxt, 3, kt);
    VMW(2);
    BAR; LGKM0; MFMA_PAIR(3); BAR;
    bufo = nxt;
  }
  // final tile (buf 1), no staging
  RD_B_ALL(bufo); RD_A_PAIR(bufo, 0);
  BAR; LGKM0; MFMA_PAIR(0); BAR;
  RD_A_PAIR(bufo, 1);
  VMW(0);
  BAR; LGKM0; MFMA_PAIR(1); BAR;
  RD_A_PAIR(bufo, 2);
  BAR; LGKM0; MFMA_PAIR(2); BAR;
  RD_A_PAIR(bufo, 3);
  BAR; LGKM0; MFMA_PAIR(3); BAR;

  // epilogue: C/D layout col = lane&15, row = (lane>>4)*4 + j  [m89-verified]
  const int cb0 = bn * 256 + wn * 64 + r16;
  float bv[4];
#pragma unroll
  for (int n = 0; n < 4; ++n) bv[n] = bias[cb0 + n * 16];
#pragma unroll
  for (int m = 0; m < 8; ++m) {
#pragma unroll
    for (int j = 0; j < 4; ++j) {
      int row = bm * 256 + wm * 128 + m * 16 + g * 4 + j;
      float* Crow = C + (size_t)row * N_DIM + cb0;
#pragma unroll
      for (int n = 0; n < 4; ++n) Crow[n * 16] = acc[m][n][j] + bv[n];
    }
  }
}

extern "C" void kernel_launch(void* const* d_in, const int* in_sizes, int n_in,
                              void* d_out, int out_size, void* d_ws, size_t ws_size,
                              hipStream_t stream) {
  const float* x     = (const float*)d_in[0];
  const float* cb    = (const float*)d_in[1];
  const int*   idx   = (const int*)d_in[2];
  const int*   base  = (const int*)d_in[3];
  const float* scale = (const float*)d_in[4];
  const float* zero  = (const float*)d_in[5];
  const float* bias  = (const float*)d_in[6];
  float* out = (float*)d_out;

  // workspace: Wq bf16 [N,K] (32 MiB) | x bf16 [M,K] (64 MiB)
  unsigned short* Wq = (unsigned short*)d_ws;
  unsigned short* Xb = (unsigned short*)((char*)d_ws + (size_t)N_DIM * K_DIM * 2);

  dequant_kernel<<<L_BLK / 256, 256, 0, stream>>>(cb, idx, base, scale, zero, Wq);
  xconv_kernel<<<(M_DIM * K_DIM / 8) / 256, 256, 0, stream>>>(x, Xb);
  gemm_bt<<<(M_DIM / 256) * (N_DIM / 256), 512, 0, stream>>>(Xb, Wq, bias, out);
}